// Round 1
// baseline (593.276 us; speedup 1.0000x reference)
//
#include <hip/hip_runtime.h>

// Causal per-channel FIR via FFT (fft_size=16384) implemented as packed
// 8192-point complex FFTs. B=8, N=8192, D=512, NUM_FREQS=512.
//
// Pipeline:
//   K0: spec[d][k] (k=0..8192) = rfft(causal_window(irfft(interp(coeffs)))) / 8192
//   K1: transpose/pack  x(B,N,D) -> zin[(d*8+b)][n'] = x[b][2n'][d] + i*x[b][2n'+1][d]
//   K2: per-seq: Z=FFT(z); unpack->Y=X*S->repack; z'=IFFT(Z'); store first 4096 cplx
//   K3: transpose/unpack yout -> out(B,N,D)

#define FFT_M 8192
#define SPEC_LEN 8193

constexpr float PI_F = 3.14159265358979323846f;

// XOR swizzle: folds high address bits into low 4 to break power-of-2 stride
// bank conflicts; bijective (modifies only bits 0..3 based on bits >=4).
__device__ __forceinline__ int swz(int k) {
    return k ^ (((k >> 4) ^ (k >> 8) ^ (k >> 12)) & 15);
}

// Generalized digit reversal for radix sequence [4,4,4,2,4,4,4] (palindromic
// => involution, so the permutation can be done with in-place swaps).
__device__ __forceinline__ int rev13(int k) {
    int d1 = k & 3, d2 = (k >> 2) & 3, d3 = (k >> 4) & 3, d4 = (k >> 6) & 1;
    int d5 = (k >> 7) & 3, d6 = (k >> 9) & 3, d7 = (k >> 11) & 3;
    return (d1 << 11) | (d2 << 9) | (d3 << 7) | (d4 << 6) | (d5 << 4) | (d6 << 2) | d7;
}

__device__ __forceinline__ float2 cmul(float2 a, float2 b) {
    return make_float2(a.x * b.x - a.y * b.y, a.x * b.y + a.y * b.x);
}

// Radix-4 DIT stage, 2048 butterflies, 512 threads. sign=-1 fwd, +1 inv.
template <int L>
__device__ void r4stage(float2* s, int tid, float sign) {
    constexpr float invL = 1.0f / (float)L;
    #pragma unroll
    for (int t = 0; t < 4; ++t) {
        int j = tid + t * 512;
        int pos = j & (L - 1);
        int blk = j - pos;            // block*L
        int i0 = 4 * blk + pos;       // block*4L + pos
        float2 a  = s[swz(i0)];
        float2 b  = s[swz(i0 + L)];
        float2 c  = s[swz(i0 + 2 * L)];
        float2 dd = s[swz(i0 + 3 * L)];
        float th = sign * (PI_F * 0.5f) * (float)pos * invL;  // sign*2pi*pos/(4L)
        float sn, cs;
        __sincosf(th, &sn, &cs);
        float2 w1 = make_float2(cs, sn);
        float2 w2 = cmul(w1, w1);
        float2 w3 = cmul(w2, w1);
        b = cmul(b, w1); c = cmul(c, w2); dd = cmul(dd, w3);
        float2 t0 = make_float2(a.x + c.x, a.y + c.y);
        float2 t1 = make_float2(a.x - c.x, a.y - c.y);
        float2 t2 = make_float2(b.x + dd.x, b.y + dd.y);
        float2 t3 = make_float2(b.x - dd.x, b.y - dd.y);
        float2 j3 = make_float2(-sign * t3.y, sign * t3.x);   // i*sign*t3
        s[swz(i0)]         = make_float2(t0.x + t2.x, t0.y + t2.y);
        s[swz(i0 + L)]     = make_float2(t1.x + j3.x, t1.y + j3.y);
        s[swz(i0 + 2 * L)] = make_float2(t0.x - t2.x, t0.y - t2.y);
        s[swz(i0 + 3 * L)] = make_float2(t1.x - j3.x, t1.y - j3.y);
    }
    __syncthreads();
}

// Radix-2 DIT stage at L=64 (the middle digit), 4096 butterflies.
__device__ void r2stage(float2* s, int tid, float sign) {
    #pragma unroll
    for (int t = 0; t < 8; ++t) {
        int j = tid + t * 512;
        int pos = j & 63;
        int blk = j - pos;
        int i0 = 2 * blk + pos;
        float2 a = s[swz(i0)];
        float2 b = s[swz(i0 + 64)];
        float sn, cs;
        __sincosf(sign * (PI_F / 64.0f) * (float)pos, &sn, &cs);  // sign*2pi*pos/128
        float2 wb = cmul(b, make_float2(cs, sn));
        s[swz(i0)]      = make_float2(a.x + wb.x, a.y + wb.y);
        s[swz(i0 + 64)] = make_float2(a.x - wb.x, a.y - wb.y);
    }
    __syncthreads();
}

// In-place 8192-pt complex FFT, natural order in/out. 512 threads. No 1/M.
__device__ void fft8192(float2* s, int tid, float sign) {
    #pragma unroll
    for (int t = 0; t < 16; ++t) {
        int k = tid + t * 512;
        int r = rev13(k);
        if (r > k) {
            float2 a = s[swz(k)];
            float2 b = s[swz(r)];
            s[swz(k)] = b;
            s[swz(r)] = a;
        }
    }
    __syncthreads();
    r4stage<1>(s, tid, sign);
    r4stage<4>(s, tid, sign);
    r4stage<16>(s, tid, sign);
    r2stage(s, tid, sign);
    r4stage<128>(s, tid, sign);
    r4stage<512>(s, tid, sign);
    r4stage<2048>(s, tid, sign);
}

// a[idx], idx in [0,8192]: a[0]=dc, a[1+j]=linear interp of coeffs (512->8192,
// half-pixel align_corners=False), matching the reference bit-for-bit in fp32.
__device__ __forceinline__ float aval(const float* C, float dcv, int idx) {
    if (idx == 0) return dcv;
    int j = idx - 1;
    float src = ((float)j + 0.5f) * 0.0625f - 0.5f;
    src = fminf(fmaxf(src, 0.0f), 511.0f);
    int lo = (int)floorf(src);
    int hi = min(lo + 1, 511);
    float w = src - (float)lo;
    return C[lo] * (1.0f - w) + C[hi] * w;
}

// K0: build spec[d][0..8192] = rfft16384(window(irfft16384(a))) * (1/8192).
// (the extra 1/8192 pre-applies K2's inverse-FFT normalization)
__global__ __launch_bounds__(512) void k0_spec(const float* __restrict__ coeffs,
                                               const float* __restrict__ dc,
                                               float2* __restrict__ spec) {
    __shared__ float2 sbuf[FFT_M];
    int d = blockIdx.x;
    int tid = threadIdx.x;
    const float* C = coeffs + d * 512;
    float dcv = dc[d];
    // Z_A[k] = Ae + i*Ao, Ae=(a[k]+a[M-k])/2, Ao=((a[k]-a[M-k])/2)*e^{+i pi k/M}
    #pragma unroll
    for (int t = 0; t < 16; ++t) {
        int k = tid + t * 512;
        float ak = aval(C, dcv, k);
        float am = aval(C, dcv, 8192 - k);
        float Ae = 0.5f * (ak + am);
        float Ao = 0.5f * (ak - am);
        float sn, cs;
        __sincosf((PI_F / 8192.0f) * (float)k, &sn, &cs);
        sbuf[swz(k)] = make_float2(Ae - Ao * sn, Ao * cs);
    }
    __syncthreads();
    fft8192(sbuf, tid, 1.0f);   // inverse (raw); t[2n],t[2n+1] = Re,Im * 1/8192
    // causal Hilbert window: h[0]=t0, h[1..8191]=2t, h[8192]=t, h[>8192]=0;
    // repack z2[n] = h[2n] + i*h[2n+1]
    #pragma unroll
    for (int t = 0; t < 16; ++t) {
        int n = tid + t * 512;
        float2 z = sbuf[swz(n)];
        float te = z.x * (1.0f / 8192.0f);
        float to = z.y * (1.0f / 8192.0f);
        int m0 = 2 * n;
        float he = (m0 == 0) ? te : ((m0 < 8192) ? 2.0f * te : ((m0 == 8192) ? te : 0.0f));
        float ho = (m0 + 1 < 8192) ? 2.0f * to : 0.0f;
        sbuf[swz(n)] = make_float2(he, ho);
    }
    __syncthreads();
    fft8192(sbuf, tid, -1.0f);  // forward
    // unpack packed-real FFT: spec[k] = Xe + e^{-i pi k/M} * Xo, k=0..8192
    float2* Sd = spec + (size_t)d * SPEC_LEN;
    const float scale = 1.0f / 8192.0f;
    #pragma unroll
    for (int t = 0; t < 8; ++t) {
        int k = tid + t * 512;
        if (k == 0) {
            float2 Z0 = sbuf[swz(0)];
            Sd[0]    = make_float2((Z0.x + Z0.y) * scale, 0.0f);
            Sd[8192] = make_float2((Z0.x - Z0.y) * scale, 0.0f);
            float2 Z4 = sbuf[swz(4096)];
            Sd[4096] = make_float2(Z4.x * scale, -Z4.y * scale);  // conj(Z[M/2])
        } else {
            int km = 8192 - k;
            float2 Zk = sbuf[swz(k)];
            float2 Zm = sbuf[swz(km)];
            float2 Xe = make_float2((Zk.x + Zm.x) * 0.5f, (Zk.y - Zm.y) * 0.5f);
            float2 dz = make_float2((Zk.x - Zm.x) * 0.5f, (Zk.y + Zm.y) * 0.5f);
            float2 Xo = make_float2(dz.y, -dz.x);                 // -i*dz
            float sn, cs;
            __sincosf(-(PI_F / 8192.0f) * (float)k, &sn, &cs);
            float2 wXo = cmul(make_float2(cs, sn), Xo);
            Sd[k]  = make_float2((Xe.x + wXo.x) * scale, (Xe.y + wXo.y) * scale);
            Sd[km] = make_float2((Xe.x - wXo.x) * scale, -(Xe.y - wXo.y) * scale);
        }
    }
}

// K1: x(B,N,D) -> zin[(d*8+b)*4096 + n'] = {x[b][2n'][d], x[b][2n'+1][d]}
__global__ __launch_bounds__(256) void k1_pack(const float* __restrict__ x,
                                               float2* __restrict__ zin) {
    __shared__ float tile[64][33];
    int bb = blockIdx.z;            // b
    int nt = blockIdx.x;            // n' tile (32 wide -> 64 time rows)
    int dt = blockIdx.y;            // d tile (32)
    int tx = threadIdx.x & 31, ty = threadIdx.x >> 5;
    const float* xb = x + (size_t)bb * 8192 * 512;
    int n0 = nt * 64;
    int d0 = dt * 32;
    #pragma unroll
    for (int r = 0; r < 8; ++r) {
        int row = ty + r * 8;       // 0..63
        tile[row][tx] = xb[(size_t)(n0 + row) * 512 + d0 + tx];
    }
    __syncthreads();
    #pragma unroll
    for (int r = 0; r < 4; ++r) {
        int dl = ty + r * 8;        // 0..31
        int d  = d0 + dl;
        int np = nt * 32 + tx;
        float2 v = make_float2(tile[2 * tx][dl], tile[2 * tx + 1][dl]);
        zin[((size_t)(d * 8 + bb)) * 4096 + np] = v;
    }
}

// K2: per-sequence packed-real FFT conv. zin/yout may alias (in-place safe:
// all reads land in LDS before any global write of this workgroup's region).
__global__ __launch_bounds__(512) void k2_conv(const float2* zin,
                                               const float2* __restrict__ spec,
                                               float2* yout) {
    __shared__ float2 sbuf[FFT_M];
    int wg = blockIdx.x;            // seq = d*8 + b
    int d = wg >> 3;
    int tid = threadIdx.x;
    const float2* zi = zin + (size_t)wg * 4096;
    #pragma unroll
    for (int t = 0; t < 8; ++t) {
        int n = tid + t * 512;
        sbuf[swz(n)] = zi[n];                        // x packed pairs
        sbuf[swz(n + 4096)] = make_float2(0.0f, 0.0f); // zero padding
    }
    __syncthreads();
    fft8192(sbuf, tid, -1.0f);
    // fused unpack -> multiply by spec -> repack, on pairs (k, M-k)
    const float2* S = spec + (size_t)d * SPEC_LEN;
    #pragma unroll
    for (int t = 0; t < 8; ++t) {
        int k = tid + t * 512;
        if (k == 0) {
            float2 Z0 = sbuf[swz(0)];
            float X0 = Z0.x + Z0.y;                  // X[0] (real)
            float XM = Z0.x - Z0.y;                  // X[M] (real)
            float2 S0 = S[0], SM = S[8192];
            float2 Y0 = make_float2(X0 * S0.x, X0 * S0.y);
            float2 YM = make_float2(XM * SM.x, XM * SM.y);
            float2 Ye = make_float2((Y0.x + YM.x) * 0.5f, (Y0.y - YM.y) * 0.5f);
            float2 Yo = make_float2((Y0.x - YM.x) * 0.5f, (Y0.y + YM.y) * 0.5f);
            sbuf[swz(0)] = make_float2(Ye.x - Yo.y, Ye.y + Yo.x);  // Ye + i*Yo
            float2 Z4 = sbuf[swz(4096)];             // self-paired bin M/2
            float2 Y4 = cmul(make_float2(Z4.x, -Z4.y), S[4096]);
            sbuf[swz(4096)] = make_float2(Y4.x, -Y4.y);
        } else {
            int km = 8192 - k;
            float2 Zk = sbuf[swz(k)];
            float2 Zm = sbuf[swz(km)];
            float2 Xe = make_float2((Zk.x + Zm.x) * 0.5f, (Zk.y - Zm.y) * 0.5f);
            float2 dz = make_float2((Zk.x - Zm.x) * 0.5f, (Zk.y + Zm.y) * 0.5f);
            float2 Xo = make_float2(dz.y, -dz.x);
            float sn, cs;
            __sincosf(-(PI_F / 8192.0f) * (float)k, &sn, &cs);
            float2 w = make_float2(cs, sn);          // e^{-i pi k / M}
            float2 wXo = cmul(w, Xo);
            float2 Xk = make_float2(Xe.x + wXo.x, Xe.y + wXo.y);
            float2 Xm = make_float2(Xe.x - wXo.x, -(Xe.y - wXo.y)); // conj(Xe-wXo)
            float2 Yk = cmul(Xk, S[k]);
            float2 Ym = cmul(Xm, S[km]);
            float2 Ye = make_float2((Yk.x + Ym.x) * 0.5f, (Yk.y - Ym.y) * 0.5f);
            float2 dy = make_float2((Yk.x - Ym.x) * 0.5f, (Yk.y + Ym.y) * 0.5f);
            float2 Yo = cmul(make_float2(cs, -sn), dy);             // *e^{+i pi k/M}
            sbuf[swz(k)]  = make_float2(Ye.x - Yo.y, Ye.y + Yo.x);  // Ye + i*Yo
            sbuf[swz(km)] = make_float2(Ye.x + Yo.y, Yo.x - Ye.y);  // conj(Ye - i*Yo)
        }
    }
    __syncthreads();
    fft8192(sbuf, tid, 1.0f);      // inverse (1/M folded into spec)
    float2* yo = yout + (size_t)wg * 4096;
    #pragma unroll
    for (int t = 0; t < 8; ++t) {
        int n = tid + t * 512;     // first 4096 complex = out samples 0..8191
        yo[n] = sbuf[swz(n)];
    }
}

// K3: yout[(d*8+b)][n'] -> out[b][2n'][d], out[b][2n'+1][d]
__global__ __launch_bounds__(256) void k3_unpack(const float2* __restrict__ yout,
                                                 float* __restrict__ out) {
    __shared__ float2 tile[32][33];
    int bb = blockIdx.z, nt = blockIdx.x, dt = blockIdx.y;
    int tx = threadIdx.x & 31, ty = threadIdx.x >> 5;
    int d0 = dt * 32, np0 = nt * 32;
    #pragma unroll
    for (int r = 0; r < 4; ++r) {
        int dl = ty + r * 8;
        tile[dl][tx] = yout[((size_t)((d0 + dl) * 8 + bb)) * 4096 + np0 + tx];
    }
    __syncthreads();
    float* ob = out + (size_t)bb * 8192 * 512;
    #pragma unroll
    for (int r = 0; r < 4; ++r) {
        int nl = ty + r * 8;
        int n  = np0 + nl;
        float2 v = tile[tx][nl];
        ob[(size_t)(2 * n) * 512 + d0 + tx]     = v.x;
        ob[(size_t)(2 * n + 1) * 512 + d0 + tx] = v.y;
    }
}

extern "C" void kernel_launch(void* const* d_in, const int* in_sizes, int n_in,
                              void* d_out, int out_size, void* d_ws, size_t ws_size,
                              hipStream_t stream) {
    const float* x      = (const float*)d_in[0];   // (8, 8192, 512)
    const float* coeffs = (const float*)d_in[1];   // (512, 512)
    const float* dc     = (const float*)d_in[2];   // (512, 1)
    float* out = (float*)d_out;                    // (8, 8192, 512)

    // ws layout: [spec: 512*8193 float2 = 33,558,528 B][zbuf: 4096*4096 float2 = 134,217,728 B]
    float2* spec = (float2*)d_ws;
    float2* zbuf = (float2*)((char*)d_ws + (size_t)512 * SPEC_LEN * sizeof(float2));

    k0_spec<<<512, 512, 0, stream>>>(coeffs, dc, spec);
    k1_pack<<<dim3(128, 16, 8), 256, 0, stream>>>(x, zbuf);
    k2_conv<<<4096, 512, 0, stream>>>(zbuf, spec, zbuf);   // in-place per-wg
    k3_unpack<<<dim3(128, 16, 8), 256, 0, stream>>>(zbuf, out);
}